// Round 1
// baseline (288.449 us; speedup 1.0000x reference)
//
#include <hip/hip_runtime.h>
#include <hip/hip_fp16.h>

#define N_NODES 100000
#define N_EDGES 1600000
#define N_BUCKETS 256
#define BUCKET_NODES 391      // 256*391 = 100096 >= N_NODES
#define BKT_BLOCKS 512
#define CAP_E 8192            // raw edges per bucket: mean 6250
#define CAP_C 12288           // padded(8) col slots per bucket: mean ~7800
#define DUMMY N_NODES         // zero feature row (byte offset DUMMY*128)

typedef unsigned short u16;
typedef _Float16 f16x8 __attribute__((ext_vector_type(8)));
typedef float f32x4 __attribute__((ext_vector_type(4)));

__device__ __forceinline__ u16 f2h(float f) {
    return __half_as_ushort(__float2half_rn(f));
}

__device__ __forceinline__ void acc8(float* acc, uint4 q) {
    unsigned v[4] = {q.x, q.y, q.z, q.w};
#pragma unroll
    for (int i = 0; i < 4; ++i) {
        __half2 h = *reinterpret_cast<__half2*>(&v[i]);
        float2 f = __half22float2(h);
        acc[2 * i] += f.x;
        acc[2 * i + 1] += f.y;
    }
}

// ---- phase 1: bucket edges into CONTIGUOUS per-bucket runs (R8 form). ----
__global__ __launch_bounds__(256) void k_bucket(const int* __restrict__ src,
                                                const int* __restrict__ dst,
                                                int* __restrict__ btot,
                                                int* __restrict__ ebuf) {
    __shared__ int cnt[N_BUCKETS], base_s[N_BUCKETS];
    const int CS = N_EDGES / BKT_BLOCKS;  // 3125
    int t = threadIdx.x;
    int beg = blockIdx.x * CS, end = beg + CS;
    for (int i = t; i < N_BUCKETS; i += 256) cnt[i] = 0;
    __syncthreads();
    for (int e = beg + t; e < end; e += 256)
        atomicAdd(&cnt[(unsigned)dst[e] / BUCKET_NODES], 1);
    __syncthreads();
    for (int i = t; i < N_BUCKETS; i += 256) {
        base_s[i] = atomicAdd(&btot[i], cnt[i]);
        cnt[i] = 0;  // reuse as local cursor
    }
    __syncthreads();
    for (int e = beg + t; e < end; e += 256) {
        int d = dst[e], s = src[e];
        int b = (unsigned)d / BUCKET_NODES;
        int l = atomicAdd(&cnt[b], 1);
        ebuf[b * CAP_E + base_s[b] + l] = s | ((d - b * BUCKET_NODES) << 17);
    }
}

// ---- phase 2: per-bucket LDS bin; PAD-8 rows; col = byte offsets; 16-entry
//      DUMMY guard after each bucket's run; fused xs(fp16) = z*dinv. ----
__global__ __launch_bounds__(1024) void k_build(const int* __restrict__ btot,
                                                const int* __restrict__ ebuf,
                                                int* __restrict__ col,
                                                int2* __restrict__ rowinfo,
                                                float* __restrict__ dinv,
                                                const float* __restrict__ z,
                                                u16* __restrict__ xs,
                                                u16* __restrict__ xs_other) {
    __shared__ int deg[BUCKET_NODES];
    __shared__ int cur[BUCKET_NODES];
    __shared__ int sm[512];
    __shared__ int cls[CAP_C];
    int b = blockIdx.x, t = threadIdx.x;
    int nb = b * BUCKET_NODES;
    int nn = N_NODES - nb < BUCKET_NODES ? N_NODES - nb : BUCKET_NODES;
    int ne = btot[b];
    const int* eb = ebuf + b * CAP_E;

    for (int i = t; i < BUCKET_NODES; i += 1024) deg[i] = 0;
    __syncthreads();
    for (int e = t; e < ne; e += 1024) atomicAdd(&deg[eb[e] >> 17], 1);
    __syncthreads();

    // pad-to-8 lengths, inclusive Hillis-Steele scan over 512 slots (nn<512)
    int v = (t < nn) ? ((deg[t] + 7) & ~7) : 0;
    if (t < 512) sm[t] = v;
    __syncthreads();
    for (int off = 1; off < 512; off <<= 1) {
        int u = (t >= off && t < 512) ? sm[t - off] : 0;
        __syncthreads();
        if (t < 512) sm[t] += u;
        __syncthreads();
    }
    int total = sm[511];
    int colbase = b * CAP_C;
    if (t < nn) {
        int off0 = sm[t] - v;
        cur[t] = off0;
        rowinfo[nb + t] = make_int2(colbase + off0, v);
        dinv[nb + t] = rsqrtf((float)deg[t] + 1.0f);
    }
    __syncthreads();
    for (int i = t; i < total; i += 1024) cls[i] = DUMMY << 7;  // pads pre-filled
    __syncthreads();
    for (int e = t; e < ne; e += 1024) {
        int pe = eb[e];
        int l = atomicAdd(&cur[pe >> 17], 1);
        cls[l] = (pe & 0x1FFFF) << 7;  // byte offset of src row
    }
    __syncthreads();
    for (int i = t; i < total; i += 1024) col[colbase + i] = cls[i];
    if (t < 16) col[colbase + total + t] = DUMMY << 7;  // guard for clamped reads

    // fused scale: xs(fp16) = z * dinv for this bucket's rows
    const float4* zz = (const float4*)(z + (size_t)nb * 64);
    uint2* xx = (uint2*)(xs + (size_t)nb * 64);
    for (int i = t; i < nn * 16; i += 1024) {
        float4 vv = zz[i];
        float dd = rsqrtf((float)deg[i >> 4] + 1.0f);
        unsigned p0 = (unsigned)f2h(vv.x * dd) | ((unsigned)f2h(vv.y * dd) << 16);
        unsigned p1 = (unsigned)f2h(vv.z * dd) | ((unsigned)f2h(vv.w * dd) << 16);
        xx[i] = make_uint2(p0, p1);
    }
    if (b == 0 && t < 8) {  // zero dummy rows of both fp16 feature buffers
        ((uint4*)(xs + (size_t)N_NODES * 64))[t] = make_uint4(0, 0, 0, 0);
        ((uint4*)(xs_other + (size_t)N_NODES * 64))[t] = make_uint4(0, 0, 0, 0);
    }
}

// ---- gather-only aggregation, pad-8 rows:
//      h[n] = fp16( dinv[n]*(sum_{s in row(n)} xs[s] + xs[n]) ).
//      Dual node per wave, 2x software-pipelined 16-slot main iters
//      (8 feature gathers + 4 col loads in flight) + one 8-slot tail.
//      Exhausted iters clamp to row block 0 (guard makes this safe),
//      accumulation predicated. Self rows prefetched across the loop. ----
__global__ __launch_bounds__(256, 4) void k_agg(const int2* __restrict__ rowinfo,
                                                const int* __restrict__ col,
                                                const float* __restrict__ dinv,
                                                const u16* __restrict__ xs,
                                                u16* __restrict__ h) {
    const int lane = threadIdx.x & 63;
    const int eighth = lane >> 3;
    const int fh = lane & 7;
    const char* xb = (const char*)xs;
    int wave = (blockIdx.x * blockDim.x + threadIdx.x) >> 6;
    int nwaves = (gridDim.x * blockDim.x) >> 6;

    for (int n0 = wave * 2; n0 < N_NODES; n0 += nwaves * 2) {
        int u0 = __builtin_amdgcn_readfirstlane(n0);
        int u1 = u0 + 1;
        bool has1 = (u1 < N_NODES);  // wave-uniform
        int2 r0 = rowinfo[u0];
        int2 r1 = has1 ? rowinfo[u1] : r0;
        int it0 = r0.y >> 4, it1 = r1.y >> 4;
        int itm = it0 > it1 ? it0 : it1;

        // self rows + dinv issued up-front, in flight across the gather loop
        uint4 qs0 = *(const uint4*)(xb + (size_t)u0 * 128 + fh * 16);
        uint4 qs1 = *(const uint4*)(xb + (size_t)u1 * 128 + fh * 16);
        float d0 = dinv[u0];
        float d1 = has1 ? dinv[u1] : 0.f;

        float a0[8] = {0.f, 0.f, 0.f, 0.f, 0.f, 0.f, 0.f, 0.f};
        float a1[8] = {0.f, 0.f, 0.f, 0.f, 0.f, 0.f, 0.f, 0.f};
        for (int r = 0; r < itm; r += 2) {
            int rb = r + 1;
            int oa0 = (r  < it0) ? (r  << 4) : 0;
            int oa1 = (r  < it1) ? (r  << 4) : 0;
            int ob0 = (rb < it0) ? (rb << 4) : 0;
            int ob1 = (rb < it1) ? (rb << 4) : 0;
            int2 ca = *(const int2*)(col + r0.x + oa0 + 2 * eighth);
            int2 cb = *(const int2*)(col + r1.x + oa1 + 2 * eighth);
            int2 cc = *(const int2*)(col + r0.x + ob0 + 2 * eighth);
            int2 cd = *(const int2*)(col + r1.x + ob1 + 2 * eighth);
            uint4 qa = *(const uint4*)(xb + (unsigned)ca.x + fh * 16);
            uint4 qb = *(const uint4*)(xb + (unsigned)ca.y + fh * 16);
            uint4 qc = *(const uint4*)(xb + (unsigned)cb.x + fh * 16);
            uint4 qd = *(const uint4*)(xb + (unsigned)cb.y + fh * 16);
            uint4 qe = *(const uint4*)(xb + (unsigned)cc.x + fh * 16);
            uint4 qf = *(const uint4*)(xb + (unsigned)cc.y + fh * 16);
            uint4 qg = *(const uint4*)(xb + (unsigned)cd.x + fh * 16);
            uint4 qh = *(const uint4*)(xb + (unsigned)cd.y + fh * 16);
            if (r  < it0) { acc8(a0, qa); acc8(a0, qb); }
            if (r  < it1) { acc8(a1, qc); acc8(a1, qd); }
            if (rb < it0) { acc8(a0, qe); acc8(a0, qf); }
            if (rb < it1) { acc8(a1, qg); acc8(a1, qh); }
        }
        int t0 = (r0.y >> 3) & 1, t1 = (r1.y >> 3) & 1;
        if (t0 | t1) {  // 8-slot tail: one slot per lane-group
            int s0 = col[r0.x + (it0 << 4) + eighth];
            int s1 = col[r1.x + (it1 << 4) + eighth];
            uint4 q0 = *(const uint4*)(xb + (unsigned)s0 + fh * 16);
            uint4 q1 = *(const uint4*)(xb + (unsigned)s1 + fh * 16);
            if (t0) acc8(a0, q0);
            if (t1) acc8(a1, q1);
        }

#pragma unroll
        for (int m = 8; m <= 32; m <<= 1) {
#pragma unroll
            for (int j = 0; j < 8; ++j) {
                a0[j] += __shfl_xor(a0[j], m, 64);
                a1[j] += __shfl_xor(a1[j], m, 64);
            }
        }
        float s0[8] = {0.f, 0.f, 0.f, 0.f, 0.f, 0.f, 0.f, 0.f};
        float s1[8] = {0.f, 0.f, 0.f, 0.f, 0.f, 0.f, 0.f, 0.f};
        acc8(s0, qs0); acc8(s1, qs1);
        uint4 p0, p1;
        u16* pp0 = (u16*)&p0;
        u16* pp1 = (u16*)&p1;
#pragma unroll
        for (int j = 0; j < 8; ++j) {
            pp0[j] = f2h((a0[j] + s0[j]) * d0);
            pp1[j] = f2h((a1[j] + s1[j]) * d1);
        }
        if (eighth == 0) ((uint4*)(h + (size_t)u0 * 64))[fh] = p0;
        if (has1 && eighth == 1) ((uint4*)(h + (size_t)u1 * 64))[fh] = p1;
    }
}

// ---- MFMA matvec: out = epi( h @ W + b ), 16-row chunks per wave.
//      mfma_f32_16x16x32_f16: A[m=lane&15][k=quad*8+j], B[k=quad*8+j][n=lane&15],
//      D[row=quad*4+reg][col=lane&15]. B fragments are COLUMN-PERMUTED so that
//      register t of the accumulator owns output column 4*l16+t: each lane's 4
//      outputs per row are contiguous -> one 8B (fp16) / 16B (f32) store per
//      row-slice instead of 16 scalar 2B stores. Memory layout of the output
//      is unchanged (canonical feature order). ----
__global__ __launch_bounds__(256) void k_mv(const u16* __restrict__ h,
                                            const float* __restrict__ W,
                                            const float* __restrict__ bias,
                                            const float* __restrict__ dinv,
                                            u16* __restrict__ outh,
                                            float* __restrict__ outf, int hidden) {
    const int lane = threadIdx.x & 63;
    const int quad = lane >> 4;
    const int l16 = lane & 15;

    // B fragments: register t, MFMA col n=l16 holds W[k][4*l16+t], k=quad*8+32c+j
    f16x8 bfr[4][2];
#pragma unroll
    for (int t = 0; t < 4; ++t)
#pragma unroll
        for (int c = 0; c < 2; ++c)
#pragma unroll
            for (int j = 0; j < 8; ++j)
                bfr[t][c][j] = (_Float16)W[(quad * 8 + 32 * c + j) * 64 + 4 * l16 + t];
    float bv[4];
#pragma unroll
    for (int t = 0; t < 4; ++t) bv[t] = bias[4 * l16 + t];

    int wave = (blockIdx.x * blockDim.x + threadIdx.x) >> 6;
    int nwaves = (gridDim.x * blockDim.x) >> 6;
    for (int chunk = wave; chunk < N_NODES / 16; chunk += nwaves) {
        int row0 = chunk * 16;
        const u16* hb = h + (size_t)row0 * 64;
        union { uint4 u; f16x8 f; } a0, a1;
        a0.u = *(const uint4*)(hb + l16 * 64 + quad * 8);
        a1.u = *(const uint4*)(hb + l16 * 64 + quad * 8 + 32);

        f32x4 acc[4] = {{0.f, 0.f, 0.f, 0.f}, {0.f, 0.f, 0.f, 0.f},
                        {0.f, 0.f, 0.f, 0.f}, {0.f, 0.f, 0.f, 0.f}};
#pragma unroll
        for (int t = 0; t < 4; ++t) {
            acc[t] = __builtin_amdgcn_mfma_f32_16x16x32_f16(a0.f, bfr[t][0], acc[t], 0, 0, 0);
            acc[t] = __builtin_amdgcn_mfma_f32_16x16x32_f16(a1.f, bfr[t][1], acc[t], 0, 0, 0);
        }
        float dv[4];
#pragma unroll
        for (int r = 0; r < 4; ++r) dv[r] = dinv[row0 + quad * 4 + r];
#pragma unroll
        for (int r = 0; r < 4; ++r) {
            int row = row0 + quad * 4 + r;
            float o[4];
#pragma unroll
            for (int t = 0; t < 4; ++t) o[t] = acc[t][r] + bv[t];
            if (hidden) {
                float dd = dv[r];
#pragma unroll
                for (int t = 0; t < 4; ++t) o[t] = fmaxf(o[t], 0.f) * dd;
                unsigned lo = (unsigned)f2h(o[0]) | ((unsigned)f2h(o[1]) << 16);
                unsigned hi = (unsigned)f2h(o[2]) | ((unsigned)f2h(o[3]) << 16);
                ((uint2*)(outh + (size_t)row * 64))[l16] = make_uint2(lo, hi);
            } else {
                ((float4*)(outf + (size_t)row * 64))[l16] =
                    make_float4(o[0], o[1], o[2], o[3]);
            }
        }
    }
}

extern "C" void kernel_launch(void* const* d_in, const int* in_sizes, int n_in,
                              void* d_out, int out_size, void* d_ws, size_t ws_size,
                              hipStream_t stream) {
    const float* z  = (const float*)d_in[0];
    const int* src  = (const int*)d_in[1];
    const int* dst  = (const int*)d_in[2];
    const float* W1 = (const float*)d_in[3];
    const float* b1 = (const float*)d_in[4];
    const float* W2 = (const float*)d_in[5];
    const float* b2 = (const float*)d_in[6];
    const float* W3 = (const float*)d_in[7];
    const float* b3 = (const float*)d_in[8];
    float* out = (float*)d_out;

    char* p = (char*)d_ws;
    float* dinv    = (float*)p;  p += (size_t)512 << 10;
    int2*  rowinfo = (int2*)p;   p += (size_t)1 << 20;                   // 800 KB used
    int*   btot    = (int*)p;    p += (size_t)4 << 10;                   // 1 KB used
    int*   ebuf    = (int*)p;    p += (size_t)N_BUCKETS * CAP_E * 4;     // 8 MB
    int*   col     = (int*)p;    p += (size_t)N_BUCKETS * CAP_C * 4;     // 12.6 MB
    u16*   hbuf    = (u16*)p;    p += (size_t)13 << 20;                  // 12.8 MB used
    u16*   buf0    = (u16*)p;    p += (size_t)13 << 20;                  // +dummy row
    u16*   buf1    = (u16*)p;                                            // +dummy row

    const int gA = 2048;  // 8192 waves
    const int gM = 512;   // 2048 waves, 6250 chunks grid-stride

    // ---- CSR build + fp16 scale ----
    hipMemsetAsync(btot, 0, N_BUCKETS * sizeof(int), stream);
    k_bucket<<<BKT_BLOCKS, 256, 0, stream>>>(src, dst, btot, ebuf);
    k_build<<<N_BUCKETS, 1024, 0, stream>>>(btot, ebuf, col, rowinfo, dinv, z, buf0, buf1);

    // ---- 3 layers: agg (gather) + mv (MFMA matvec) ----
    k_agg<<<gA, 256, 0, stream>>>(rowinfo, col, dinv, buf0, hbuf);
    k_mv <<<gM, 256, 0, stream>>>(hbuf, W1, b1, dinv, buf1, nullptr, 1);
    k_agg<<<gA, 256, 0, stream>>>(rowinfo, col, dinv, buf1, hbuf);
    k_mv <<<gM, 256, 0, stream>>>(hbuf, W2, b2, dinv, buf0, nullptr, 1);
    k_agg<<<gA, 256, 0, stream>>>(rowinfo, col, dinv, buf0, hbuf);
    k_mv <<<gM, 256, 0, stream>>>(hbuf, W3, b3, dinv, nullptr, out, 0);
}

// Round 2
// 261.332 us; speedup vs baseline: 1.1038x; 1.1038x over previous
//
#include <hip/hip_runtime.h>
#include <hip/hip_fp16.h>

#define N_NODES 100000
#define N_EDGES 1600000
#define N_BUCKETS 256
#define BUCKET_NODES 391      // 256*391 = 100096 >= N_NODES
#define BKT_BLOCKS 512
#define CAP_E 8192            // raw edges per bucket: mean 6250
#define CAP_C 12288           // padded(8) col slots per bucket: mean ~7800
#define DUMMY N_NODES         // zero feature row (byte offset DUMMY*128)

typedef unsigned short u16;
typedef _Float16 f16x8 __attribute__((ext_vector_type(8)));
typedef float f32x4 __attribute__((ext_vector_type(4)));

__device__ __forceinline__ u16 f2h(float f) {
    return __half_as_ushort(__float2half_rn(f));
}

__device__ __forceinline__ void acc8(float* acc, uint4 q) {
    unsigned v[4] = {q.x, q.y, q.z, q.w};
#pragma unroll
    for (int i = 0; i < 4; ++i) {
        __half2 h = *reinterpret_cast<__half2*>(&v[i]);
        float2 f = __half22float2(h);
        acc[2 * i] += f.x;
        acc[2 * i + 1] += f.y;
    }
}

// ---- phase 1: bucket edges into CONTIGUOUS per-bucket runs (R8 form). ----
__global__ __launch_bounds__(256) void k_bucket(const int* __restrict__ src,
                                                const int* __restrict__ dst,
                                                int* __restrict__ btot,
                                                int* __restrict__ ebuf) {
    __shared__ int cnt[N_BUCKETS], base_s[N_BUCKETS];
    const int CS = N_EDGES / BKT_BLOCKS;  // 3125
    int t = threadIdx.x;
    int beg = blockIdx.x * CS, end = beg + CS;
    for (int i = t; i < N_BUCKETS; i += 256) cnt[i] = 0;
    __syncthreads();
    for (int e = beg + t; e < end; e += 256)
        atomicAdd(&cnt[(unsigned)dst[e] / BUCKET_NODES], 1);
    __syncthreads();
    for (int i = t; i < N_BUCKETS; i += 256) {
        base_s[i] = atomicAdd(&btot[i], cnt[i]);
        cnt[i] = 0;  // reuse as local cursor
    }
    __syncthreads();
    for (int e = beg + t; e < end; e += 256) {
        int d = dst[e], s = src[e];
        int b = (unsigned)d / BUCKET_NODES;
        int l = atomicAdd(&cnt[b], 1);
        ebuf[b * CAP_E + base_s[b] + l] = s | ((d - b * BUCKET_NODES) << 17);
    }
}

// ---- phase 2: per-bucket LDS bin; PAD-8 rows; col = byte offsets; 16-entry
//      DUMMY guard after each bucket's run; fused xs(fp16) = z*dinv. ----
__global__ __launch_bounds__(1024) void k_build(const int* __restrict__ btot,
                                                const int* __restrict__ ebuf,
                                                int* __restrict__ col,
                                                int2* __restrict__ rowinfo,
                                                float* __restrict__ dinv,
                                                const float* __restrict__ z,
                                                u16* __restrict__ xs,
                                                u16* __restrict__ xs_other) {
    __shared__ int deg[BUCKET_NODES];
    __shared__ int cur[BUCKET_NODES];
    __shared__ int sm[512];
    __shared__ int cls[CAP_C];
    int b = blockIdx.x, t = threadIdx.x;
    int nb = b * BUCKET_NODES;
    int nn = N_NODES - nb < BUCKET_NODES ? N_NODES - nb : BUCKET_NODES;
    int ne = btot[b];
    const int* eb = ebuf + b * CAP_E;

    for (int i = t; i < BUCKET_NODES; i += 1024) deg[i] = 0;
    __syncthreads();
    for (int e = t; e < ne; e += 1024) atomicAdd(&deg[eb[e] >> 17], 1);
    __syncthreads();

    // pad-to-8 lengths, inclusive Hillis-Steele scan over 512 slots (nn<512)
    int v = (t < nn) ? ((deg[t] + 7) & ~7) : 0;
    if (t < 512) sm[t] = v;
    __syncthreads();
    for (int off = 1; off < 512; off <<= 1) {
        int u = (t >= off && t < 512) ? sm[t - off] : 0;
        __syncthreads();
        if (t < 512) sm[t] += u;
        __syncthreads();
    }
    int total = sm[511];
    int colbase = b * CAP_C;
    if (t < nn) {
        int off0 = sm[t] - v;
        cur[t] = off0;
        rowinfo[nb + t] = make_int2(colbase + off0, v);
        dinv[nb + t] = rsqrtf((float)deg[t] + 1.0f);
    }
    __syncthreads();
    for (int i = t; i < total; i += 1024) cls[i] = DUMMY << 7;  // pads pre-filled
    __syncthreads();
    for (int e = t; e < ne; e += 1024) {
        int pe = eb[e];
        int l = atomicAdd(&cur[pe >> 17], 1);
        cls[l] = (pe & 0x1FFFF) << 7;  // byte offset of src row
    }
    __syncthreads();
    for (int i = t; i < total; i += 1024) col[colbase + i] = cls[i];
    if (t < 16) col[colbase + total + t] = DUMMY << 7;  // guard for clamped reads

    // fused scale: xs(fp16) = z * dinv for this bucket's rows
    const float4* zz = (const float4*)(z + (size_t)nb * 64);
    uint2* xx = (uint2*)(xs + (size_t)nb * 64);
    for (int i = t; i < nn * 16; i += 1024) {
        float4 vv = zz[i];
        float dd = rsqrtf((float)deg[i >> 4] + 1.0f);
        unsigned p0 = (unsigned)f2h(vv.x * dd) | ((unsigned)f2h(vv.y * dd) << 16);
        unsigned p1 = (unsigned)f2h(vv.z * dd) | ((unsigned)f2h(vv.w * dd) << 16);
        xx[i] = make_uint2(p0, p1);
    }
    if (b == 0 && t < 8) {  // zero dummy rows of both fp16 feature buffers
        ((uint4*)(xs + (size_t)N_NODES * 64))[t] = make_uint4(0, 0, 0, 0);
        ((uint4*)(xs_other + (size_t)N_NODES * 64))[t] = make_uint4(0, 0, 0, 0);
    }
}

// ---- gather-only aggregation, pad-8 rows, QUAD-node waves:
//      h[n] = fp16( dinv[n]*(sum_{s in row(n)} xs[s] + xs[n]) ).
//      4 independent node streams per wave -> 8 feature gathers + 4 col
//      loads batched per iter; sched_barrier(0) pins the issue batch above
//      the accumulate block so loads stay in flight. Self rows issued ahead
//      of the main loop (broadcast lines, cheap). Exhausted-node iters clamp
//      to slot 0 (guard makes addresses safe), acc predicated. ----
__global__ __launch_bounds__(256, 4) void k_agg(const int2* __restrict__ rowinfo,
                                                const int* __restrict__ col,
                                                const float* __restrict__ dinv,
                                                const u16* __restrict__ xs,
                                                u16* __restrict__ h) {
    const int lane = threadIdx.x & 63;
    const int eighth = lane >> 3;
    const int fh = lane & 7;
    const char* xb = (const char*)xs;
    int wave = (blockIdx.x * blockDim.x + threadIdx.x) >> 6;
    int nwaves = (gridDim.x * blockDim.x) >> 6;

    for (int n0 = wave * 4; n0 < N_NODES; n0 += nwaves * 4) {
        int u0 = __builtin_amdgcn_readfirstlane(n0);  // uniform -> s_loads below
        int2 r0 = rowinfo[u0];
        int2 r1 = rowinfo[u0 + 1];
        int2 r2 = rowinfo[u0 + 2];
        int2 r3 = rowinfo[u0 + 3];
        int it0 = r0.y >> 4, it1 = r1.y >> 4, it2 = r2.y >> 4, it3 = r3.y >> 4;
        int itm = it0 > it1 ? it0 : it1;
        if (it2 > itm) itm = it2;
        if (it3 > itm) itm = it3;

        // phase A: issue r=0 cols, tail cols, self rows — all independent
        int2 c0 = *(const int2*)(col + r0.x + 2 * eighth);
        int2 c1 = *(const int2*)(col + r1.x + 2 * eighth);
        int2 c2 = *(const int2*)(col + r2.x + 2 * eighth);
        int2 c3 = *(const int2*)(col + r3.x + 2 * eighth);
        int tc0 = col[r0.x + (it0 << 4) + eighth];
        int tc1 = col[r1.x + (it1 << 4) + eighth];
        int tc2 = col[r2.x + (it2 << 4) + eighth];
        int tc3 = col[r3.x + (it3 << 4) + eighth];
        uint4 s0 = *(const uint4*)(xb + (size_t)u0 * 128 + fh * 16);
        uint4 s1 = *(const uint4*)(xb + (size_t)(u0 + 1) * 128 + fh * 16);
        uint4 s2 = *(const uint4*)(xb + (size_t)(u0 + 2) * 128 + fh * 16);
        uint4 s3 = *(const uint4*)(xb + (size_t)(u0 + 3) * 128 + fh * 16);

        float a0[8] = {0.f, 0.f, 0.f, 0.f, 0.f, 0.f, 0.f, 0.f};
        float a1[8] = {0.f, 0.f, 0.f, 0.f, 0.f, 0.f, 0.f, 0.f};
        float a2[8] = {0.f, 0.f, 0.f, 0.f, 0.f, 0.f, 0.f, 0.f};
        float a3[8] = {0.f, 0.f, 0.f, 0.f, 0.f, 0.f, 0.f, 0.f};

        for (int rr = 0; rr < itm; ++rr) {
            uint4 q0 = *(const uint4*)(xb + (unsigned)c0.x + fh * 16);
            uint4 q1 = *(const uint4*)(xb + (unsigned)c0.y + fh * 16);
            uint4 q2 = *(const uint4*)(xb + (unsigned)c1.x + fh * 16);
            uint4 q3 = *(const uint4*)(xb + (unsigned)c1.y + fh * 16);
            uint4 q4 = *(const uint4*)(xb + (unsigned)c2.x + fh * 16);
            uint4 q5 = *(const uint4*)(xb + (unsigned)c2.y + fh * 16);
            uint4 q6 = *(const uint4*)(xb + (unsigned)c3.x + fh * 16);
            uint4 q7 = *(const uint4*)(xb + (unsigned)c3.y + fh * 16);
            int rn = rr + 1;
            if (rn < itm) {  // prefetch next iteration's cols (rare path)
                c0 = *(const int2*)(col + r0.x + ((rn < it0 ? rn : 0) << 4) + 2 * eighth);
                c1 = *(const int2*)(col + r1.x + ((rn < it1 ? rn : 0) << 4) + 2 * eighth);
                c2 = *(const int2*)(col + r2.x + ((rn < it2 ? rn : 0) << 4) + 2 * eighth);
                c3 = *(const int2*)(col + r3.x + ((rn < it3 ? rn : 0) << 4) + 2 * eighth);
            }
            __builtin_amdgcn_sched_barrier(0);  // keep the 8 gathers in flight
            if (rr < it0) { acc8(a0, q0); acc8(a0, q1); }
            if (rr < it1) { acc8(a1, q2); acc8(a1, q3); }
            if (rr < it2) { acc8(a2, q4); acc8(a2, q5); }
            if (rr < it3) { acc8(a3, q6); acc8(a3, q7); }
        }

        // 8-slot tails, batched
        uint4 g0 = *(const uint4*)(xb + (unsigned)tc0 + fh * 16);
        uint4 g1 = *(const uint4*)(xb + (unsigned)tc1 + fh * 16);
        uint4 g2 = *(const uint4*)(xb + (unsigned)tc2 + fh * 16);
        uint4 g3 = *(const uint4*)(xb + (unsigned)tc3 + fh * 16);
        __builtin_amdgcn_sched_barrier(0);
        if ((r0.y >> 3) & 1) acc8(a0, g0);
        if ((r1.y >> 3) & 1) acc8(a1, g1);
        if ((r2.y >> 3) & 1) acc8(a2, g2);
        if ((r3.y >> 3) & 1) acc8(a3, g3);
        // self-loop rows: one eighth each; xor-reduce sums them in once
        if (eighth == 0) acc8(a0, s0);
        if (eighth == 1) acc8(a1, s1);
        if (eighth == 2) acc8(a2, s2);
        if (eighth == 3) acc8(a3, s3);

#pragma unroll
        for (int m = 8; m <= 32; m <<= 1) {
#pragma unroll
            for (int j = 0; j < 8; ++j) {
                a0[j] += __shfl_xor(a0[j], m, 64);
                a1[j] += __shfl_xor(a1[j], m, 64);
                a2[j] += __shfl_xor(a2[j], m, 64);
                a3[j] += __shfl_xor(a3[j], m, 64);
            }
        }
        float d0 = dinv[u0];
        float d1 = dinv[u0 + 1];
        float d2 = dinv[u0 + 2];
        float d3 = dinv[u0 + 3];
        uint4 p0, p1, p2, p3;
        u16* pp0 = (u16*)&p0;
        u16* pp1 = (u16*)&p1;
        u16* pp2 = (u16*)&p2;
        u16* pp3 = (u16*)&p3;
#pragma unroll
        for (int j = 0; j < 8; ++j) {
            pp0[j] = f2h(a0[j] * d0);
            pp1[j] = f2h(a1[j] * d1);
            pp2[j] = f2h(a2[j] * d2);
            pp3[j] = f2h(a3[j] * d3);
        }
        if (eighth == 0) ((uint4*)(h + (size_t)u0 * 64))[fh] = p0;
        if (eighth == 1) ((uint4*)(h + (size_t)(u0 + 1) * 64))[fh] = p1;
        if (eighth == 2) ((uint4*)(h + (size_t)(u0 + 2) * 64))[fh] = p2;
        if (eighth == 3) ((uint4*)(h + (size_t)(u0 + 3) * 64))[fh] = p3;
    }
}

// ---- one-time W permute: Wp[t][c][quad][l16][j] = fp16(W[quad*8+32c+j][4*l16+t])
//      so k_mv's B fragments are 8 coalesced uint4 loads per lane. ----
__global__ __launch_bounds__(256) void k_prepw(const float* __restrict__ W1,
                                               const float* __restrict__ W2,
                                               const float* __restrict__ W3,
                                               u16* __restrict__ Wp) {
    const float* W = blockIdx.x == 0 ? W1 : (blockIdx.x == 1 ? W2 : W3);
    u16* o = Wp + blockIdx.x * 4096;
    for (int f = threadIdx.x; f < 4096; f += 256) {
        int j = f & 7, l16 = (f >> 3) & 15, quad = (f >> 7) & 3;
        int c = (f >> 9) & 1, t = f >> 10;
        o[f] = f2h(W[(quad * 8 + 32 * c + j) * 64 + 4 * l16 + t]);
    }
}

// ---- MFMA matvec: out = epi( h @ W + b ), 16-row chunks per wave.
//      mfma_f32_16x16x32_f16: A[m=lane&15][k=quad*8+j], B[k=quad*8+j][n=lane&15],
//      D[row=quad*4+reg][col=lane&15]. B fragments COLUMN-PERMUTED (register t
//      owns output column 4*l16+t) and PRELOADED from Wp: one 8B (fp16) /
//      16B (f32) store per row-slice. Output memory layout canonical. ----
__global__ __launch_bounds__(256) void k_mv(const u16* __restrict__ h,
                                            const u16* __restrict__ Wp,
                                            const float* __restrict__ bias,
                                            const float* __restrict__ dinv,
                                            u16* __restrict__ outh,
                                            float* __restrict__ outf, int hidden) {
    const int lane = threadIdx.x & 63;
    const int quad = lane >> 4;
    const int l16 = lane & 15;

    const uint4* wq = (const uint4*)Wp;
    union { uint4 u; f16x8 f; } bfr[4][2];
#pragma unroll
    for (int t = 0; t < 4; ++t)
#pragma unroll
        for (int c = 0; c < 2; ++c)
            bfr[t][c].u = wq[t * 128 + c * 64 + quad * 16 + l16];
    float4 bq = ((const float4*)bias)[l16];
    float bv[4] = {bq.x, bq.y, bq.z, bq.w};

    int wave = (blockIdx.x * blockDim.x + threadIdx.x) >> 6;
    int nwaves = (gridDim.x * blockDim.x) >> 6;
    for (int chunk = wave; chunk < N_NODES / 16; chunk += nwaves) {
        int row0 = chunk * 16;
        const u16* hb = h + (size_t)row0 * 64;
        union { uint4 u; f16x8 f; } a0, a1;
        a0.u = *(const uint4*)(hb + l16 * 64 + quad * 8);
        a1.u = *(const uint4*)(hb + l16 * 64 + quad * 8 + 32);

        f32x4 acc[4] = {{0.f, 0.f, 0.f, 0.f}, {0.f, 0.f, 0.f, 0.f},
                        {0.f, 0.f, 0.f, 0.f}, {0.f, 0.f, 0.f, 0.f}};
#pragma unroll
        for (int t = 0; t < 4; ++t) {
            acc[t] = __builtin_amdgcn_mfma_f32_16x16x32_f16(a0.f, bfr[t][0].f, acc[t], 0, 0, 0);
            acc[t] = __builtin_amdgcn_mfma_f32_16x16x32_f16(a1.f, bfr[t][1].f, acc[t], 0, 0, 0);
        }
        float dv[4];
#pragma unroll
        for (int r = 0; r < 4; ++r) dv[r] = dinv[row0 + quad * 4 + r];
#pragma unroll
        for (int r = 0; r < 4; ++r) {
            int row = row0 + quad * 4 + r;
            float o[4];
#pragma unroll
            for (int t = 0; t < 4; ++t) o[t] = acc[t][r] + bv[t];
            if (hidden) {
                float dd = dv[r];
#pragma unroll
                for (int t = 0; t < 4; ++t) o[t] = fmaxf(o[t], 0.f) * dd;
                unsigned lo = (unsigned)f2h(o[0]) | ((unsigned)f2h(o[1]) << 16);
                unsigned hi = (unsigned)f2h(o[2]) | ((unsigned)f2h(o[3]) << 16);
                ((uint2*)(outh + (size_t)row * 64))[l16] = make_uint2(lo, hi);
            } else {
                ((float4*)(outf + (size_t)row * 64))[l16] =
                    make_float4(o[0], o[1], o[2], o[3]);
            }
        }
    }
}

extern "C" void kernel_launch(void* const* d_in, const int* in_sizes, int n_in,
                              void* d_out, int out_size, void* d_ws, size_t ws_size,
                              hipStream_t stream) {
    const float* z  = (const float*)d_in[0];
    const int* src  = (const int*)d_in[1];
    const int* dst  = (const int*)d_in[2];
    const float* W1 = (const float*)d_in[3];
    const float* b1 = (const float*)d_in[4];
    const float* W2 = (const float*)d_in[5];
    const float* b2 = (const float*)d_in[6];
    const float* W3 = (const float*)d_in[7];
    const float* b3 = (const float*)d_in[8];
    float* out = (float*)d_out;

    char* p = (char*)d_ws;
    float* dinv    = (float*)p;  p += (size_t)512 << 10;
    int2*  rowinfo = (int2*)p;   p += (size_t)1 << 20;                   // 800 KB used
    int*   btot    = (int*)p;    p += (size_t)4 << 10;                   // 1 KB used
    int*   ebuf    = (int*)p;    p += (size_t)N_BUCKETS * CAP_E * 4;     // 8 MB
    int*   col     = (int*)p;    p += (size_t)N_BUCKETS * CAP_C * 4;     // 12.6 MB
    u16*   hbuf    = (u16*)p;    p += (size_t)13 << 20;                  // 12.8 MB used
    u16*   buf0    = (u16*)p;    p += (size_t)13 << 20;                  // +dummy row
    u16*   buf1    = (u16*)p;    p += (size_t)13 << 20;                  // +dummy row
    u16*   wp      = (u16*)p;                                            // 24 KB

    const int gA = 2048;  // 8192 waves, 3.05 quads each
    const int gM = 1563;  // 6252 waves, ~1 chunk each

    // ---- W fragment permute + CSR build + fp16 scale ----
    k_prepw<<<3, 256, 0, stream>>>(W1, W2, W3, wp);
    hipMemsetAsync(btot, 0, N_BUCKETS * sizeof(int), stream);
    k_bucket<<<BKT_BLOCKS, 256, 0, stream>>>(src, dst, btot, ebuf);
    k_build<<<N_BUCKETS, 1024, 0, stream>>>(btot, ebuf, col, rowinfo, dinv, z, buf0, buf1);

    // ---- 3 layers: agg (gather) + mv (MFMA matvec) ----
    k_agg<<<gA, 256, 0, stream>>>(rowinfo, col, dinv, buf0, hbuf);
    k_mv <<<gM, 256, 0, stream>>>(hbuf, wp, b1, dinv, buf1, nullptr, 1);
    k_agg<<<gA, 256, 0, stream>>>(rowinfo, col, dinv, buf1, hbuf);
    k_mv <<<gM, 256, 0, stream>>>(hbuf, wp + 4096, b2, dinv, buf0, nullptr, 1);
    k_agg<<<gA, 256, 0, stream>>>(rowinfo, col, dinv, buf0, hbuf);
    k_mv <<<gM, 256, 0, stream>>>(hbuf, wp + 8192, b3, dinv, nullptr, out, 0);
}